// Round 3
// baseline (405.592 us; speedup 1.0000x reference)
//
#include <hip/hip_runtime.h>
#include <hip/hip_bf16.h>

#define IN_F   64
#define OUT_F  64
#define N_RELS 32
#define N_BAS  30
#define KROW   2048               // k = i*32 + b  (i feature 0..63, b slot 0..31)
#define B1CHUNK 8192

typedef __attribute__((ext_vector_type(8))) short short8v;
typedef __attribute__((ext_vector_type(8))) _Float16 half8v;
typedef __attribute__((ext_vector_type(4))) float f32x4;

__device__ __forceinline__ int dmin(int a, int b) { return a < b ? a : b; }
__device__ __forceinline__ unsigned short f2bf(float f) {
    __hip_bfloat16 h = __float2bfloat16(f);
    return *(unsigned short*)&h;
}

// ---------- K1: bbT[o][i*32+b] : b<30 -> basis[b][i][o], b==30 -> sw[i][o], b==31 -> (i==0)?bias[o]:0
__global__ void k_bbt(const float* __restrict__ basis, const float* __restrict__ sw,
                      const float* __restrict__ bias, __hip_bfloat16* __restrict__ bbT) {
    int idx = blockIdx.x * blockDim.x + threadIdx.x;
    if (idx >= OUT_F * KROW) return;
    int o = idx >> 11, k = idx & (KROW - 1);
    int i = k >> 5, b = k & 31;
    float v;
    if (b < N_BAS)      v = basis[((size_t)b * IN_F + i) * OUT_F + o];
    else if (b == 30)   v = sw[(size_t)i * OUT_F + o];
    else                v = (i == 0) ? bias[o] : 0.f;
    bbT[idx] = __float2bfloat16(v);
}

// ---------- K2: coarse histogram by tgt>>8 ----------
__global__ void __launch_bounds__(256)
k_b1a(const int* __restrict__ tgt, int* __restrict__ gsum, int E) {
    __shared__ int lh[256];
    int tid = threadIdx.x;
    lh[tid] = 0;
    __syncthreads();
    for (int i = blockIdx.x * blockDim.x + tid; i < E; i += gridDim.x * blockDim.x)
        atomicAdd(&lh[tgt[i] >> 8], 1);
    __syncthreads();
    if (lh[tid]) atomicAdd(&gsum[tid], lh[tid]);
}

// ---------- K3: tiny scan of coarse buckets ----------
__global__ void k_scanB(const int* __restrict__ gsum, int* __restrict__ gexcl,
                        int* __restrict__ bcur, int* __restrict__ off, int NB, int N) {
    int l = threadIdx.x;
    int a0 = (4*l+0 < NB) ? gsum[4*l+0] : 0;
    int a1 = (4*l+1 < NB) ? gsum[4*l+1] : 0;
    int a2 = (4*l+2 < NB) ? gsum[4*l+2] : 0;
    int a3 = (4*l+3 < NB) ? gsum[4*l+3] : 0;
    int s = a0 + a1 + a2 + a3;
    int sc = s;
    for (int d = 1; d < 64; d <<= 1) {
        int o = __shfl_up(sc, d, 64);
        if (l >= d) sc += o;
    }
    int base = sc - s;
    if (4*l+0 < NB) { gexcl[4*l+0] = base;          bcur[4*l+0] = base; }
    if (4*l+1 < NB) { gexcl[4*l+1] = base+a0;       bcur[4*l+1] = base+a0; }
    if (4*l+2 < NB) { gexcl[4*l+2] = base+a0+a1;    bcur[4*l+2] = base+a0+a1; }
    if (4*l+3 < NB) { gexcl[4*l+3] = base+a0+a1+a2; bcur[4*l+3] = base+a0+a1+a2; }
    if (l == 63) { gexcl[NB] = sc; off[N] = sc; }
}

// ---------- K4: coarse bucket scatter ----------
__global__ void __launch_bounds__(1024)
k_b1(const int* __restrict__ src, const int* __restrict__ tgt, const int* __restrict__ et,
     int* __restrict__ bcur, unsigned* __restrict__ ssr, int E) {
    __shared__ unsigned ls_p[B1CHUNK];
    __shared__ unsigned char ls_b[B1CHUNK];
    __shared__ int lh[256], lbase[256], gbase[256], lcur[256];
    int tid = threadIdx.x;
    int e0 = blockIdx.x * B1CHUNK;
    int n = E - e0; if (n > B1CHUNK) n = B1CHUNK;
    if (tid < 256) { lh[tid] = 0; lcur[tid] = 0; }
    __syncthreads();
    unsigned pr[8]; int br[8];
#pragma unroll
    for (int k = 0; k < 8; ++k) {
        int i = k * 1024 + tid;
        br[k] = -1;
        if (i < n) {
            int t = tgt[e0 + i];
            br[k] = t >> 8;
            pr[k] = ((unsigned)(t & 255) << 21) | ((unsigned)src[e0 + i] << 5) | (unsigned)et[e0 + i];
            atomicAdd(&lh[br[k]], 1);
        }
    }
    __syncthreads();
    if (tid < 64) {
        int a0 = lh[4*tid], a1 = lh[4*tid+1], a2 = lh[4*tid+2], a3 = lh[4*tid+3];
        int s = a0 + a1 + a2 + a3, sc = s;
        for (int d = 1; d < 64; d <<= 1) {
            int o = __shfl_up(sc, d, 64);
            if (tid >= d) sc += o;
        }
        int base = sc - s;
        lbase[4*tid] = base; lbase[4*tid+1] = base+a0;
        lbase[4*tid+2] = base+a0+a1; lbase[4*tid+3] = base+a0+a1+a2;
    }
    __syncthreads();
    if (tid < 256 && lh[tid]) gbase[tid] = atomicAdd(&bcur[tid], lh[tid]);
    __syncthreads();
#pragma unroll
    for (int k = 0; k < 8; ++k) {
        if (br[k] >= 0) {
            int pos = atomicAdd(&lcur[br[k]], 1);
            int s = lbase[br[k]] + pos;
            ls_p[s] = pr[k];
            ls_b[s] = (unsigned char)br[k];
        }
    }
    __syncthreads();
#pragma unroll
    for (int k = 0; k < 8; ++k) {
        int i = k * 1024 + tid;
        if (i < n) {
            int b = ls_b[i];
            ssr[gbase[b] + (i - lbase[b])] = ls_p[i];
        }
    }
}

// ---------- K5: per-bucket fine sort ----------
__global__ void __launch_bounds__(256)
k_b2(const unsigned* __restrict__ ssr, const int* __restrict__ gexcl,
     int* __restrict__ off, unsigned* __restrict__ ssr2, int N) {
    __shared__ int lh[256], lofs[256], lcur[256];
    int g = blockIdx.x, tid = threadIdx.x;
    int o0 = gexcl[g], o1 = gexcl[g + 1];
    lh[tid] = 0;
    __syncthreads();
    for (int i = o0 + tid; i < o1; i += 256)
        atomicAdd(&lh[ssr[i] >> 21], 1);
    __syncthreads();
    if (tid < 64) {
        int a0 = lh[4*tid], a1 = lh[4*tid+1], a2 = lh[4*tid+2], a3 = lh[4*tid+3];
        int s = a0 + a1 + a2 + a3, sc = s;
        for (int d = 1; d < 64; d <<= 1) {
            int o = __shfl_up(sc, d, 64);
            if (tid >= d) sc += o;
        }
        int base = sc - s;
        lofs[4*tid] = base; lofs[4*tid+1] = base+a0;
        lofs[4*tid+2] = base+a0+a1; lofs[4*tid+3] = base+a0+a1+a2;
    }
    __syncthreads();
    int t = (g << 8) + tid;
    if (t < N) off[t] = o0 + lofs[tid];
    lcur[tid] = o0 + lofs[tid];
    __syncthreads();
    for (int i = o0 + tid; i < o1; i += 256) {
        unsigned p = ssr[i];
        int pos = atomicAdd(&lcur[p >> 21], 1);
        ssr2[pos] = p;
    }
}

// ---------- K6: fused v6 — 4 targets/block, 2 waves/target (M-halves), high occupancy ----------
// Edge GEMM per target: Y^T[i][b] = sum_e x[src_e][i]*coeff[r_e][b], mfma_f32_16x16x32_f16.
// Wave w: tIdx=w>>1, mh=w&1 owns feats i in [mh*32, mh*32+32) -> acc[2][2] (16 AGPR).
// zb row layout k = i*32+b (bf16), XOR swizzle byte^=((row&7)<<4). Phase2: 8 waves =
// 4 colblks x 2 K-halves (K=1024, 32 steps), A-rows duplicated (l15&3); reduce 2 partials.
__global__ void __launch_bounds__(512, 8)
k_fused(const float* __restrict__ x, const unsigned* __restrict__ ssr2,
        const int* __restrict__ off, const float* __restrict__ coeff,
        const __hip_bfloat16* __restrict__ bbT, float* __restrict__ out, int N) {
    __shared__ __align__(16) unsigned char zb[4 * 4096];    // 4 targets x 2048 bf16
    __shared__ __align__(16) float pf[8 * 256];             // phase-2 partials; head aliases cofs2
    unsigned* cofs2 = (unsigned*)pf;                        // [33][16] u32 {f16 c | f16 c+16}, row32=0
    int tid = threadIdx.x;
    int w = tid >> 6, lane = tid & 63;
    int tIdx = w >> 1, mh = w & 1;
    int t0 = blockIdx.x * 4;
    int t = t0 + tIdx;

    // hoisted loads (latency hides under coeff staging + barrier)
    int offt = 0, offt1 = 0;
    float xself = 0.f;
    if (t < N) {
        offt  = off[t];
        offt1 = off[t + 1];
        xself = x[((size_t)t << 6) + (mh << 5) + (lane & 31)];
    }

    // stage coeff pairs -> LDS
    for (int idx = tid; idx < 33 * 16; idx += 512) {
        int r = idx >> 4, c = idx & 15;
        float lo = (r < 32) ? coeff[r * N_BAS + c] : 0.f;
        float hi = (r < 32 && (c + 16) < N_BAS) ? coeff[r * N_BAS + c + 16] : 0.f;
        _Float16 hl = (_Float16)lo, hh = (_Float16)hi;
        cofs2[idx] = (unsigned)*(unsigned short*)&hl | ((unsigned)*(unsigned short*)&hh << 16);
    }
    __syncthreads();

    int l15 = lane & 15, lk = lane >> 4;
    int vq = lk << 3;                      // edge-slot base of this quadrant
    int vperm = (lane & 48) << 1;          // bpermute byte base
    unsigned xadd = (unsigned)((mh << 7) + (l15 << 2));

    int s0 = __builtin_amdgcn_readfirstlane(offt);
    int s1 = __builtin_amdgcn_readfirstlane(offt1);
    int deg = (t < N) ? (s1 - s0) : 0;

    f32x4 acc00 = {0.f,0.f,0.f,0.f};
    f32x4 acc01 = acc00, acc10 = acc00, acc11 = acc00;

    if (deg > 0) {
        const char* xB = (const char*)x;
        int last = s1 - 1;
#pragma unroll 1
        for (int kt = 0; kt * 32 < deg; ++kt) {
            int base = s0 + kt * 32;
            unsigned ew = ssr2[dmin(base + (lane & 31), last)];
            int rem = deg - kt * 32;
            float xr0[8], xr1[8];
            unsigned bw[8];
#pragma unroll
            for (int j = 0; j < 8; ++j) {
                unsigned wj = (unsigned)__builtin_amdgcn_ds_bpermute(vperm + j * 4, (int)ew);
                unsigned xoff = (((wj >> 5) & 0xFFFFu) << 8) + xadd;
                unsigned rrow = ((vq + j) < rem) ? (wj & 31u) : 32u;   // pad -> zero row
                bw[j] = cofs2[(rrow << 4) + l15];
                xr0[j] = *(const float*)(xB + xoff);
                xr1[j] = *(const float*)(xB + xoff + 64);
            }
            union { unsigned short u[8]; half8v h; } bf0, bf1;
            union { _Float16 f[8]; half8v h; } a0, a1;
#pragma unroll
            for (int j = 0; j < 8; ++j) {
                bf0.u[j] = (unsigned short)(bw[j] & 0xFFFFu);
                bf1.u[j] = (unsigned short)(bw[j] >> 16);
                a0.f[j] = (_Float16)xr0[j];
                a1.f[j] = (_Float16)xr1[j];
            }
            acc00 = __builtin_amdgcn_mfma_f32_16x16x32_f16(a0.h, bf0.h, acc00, 0, 0, 0);
            acc01 = __builtin_amdgcn_mfma_f32_16x16x32_f16(a0.h, bf1.h, acc01, 0, 0, 0);
            acc10 = __builtin_amdgcn_mfma_f32_16x16x32_f16(a1.h, bf0.h, acc10, 0, 0, 0);
            acc11 = __builtin_amdgcn_mfma_f32_16x16x32_f16(a1.h, bf1.h, acc11, 0, 0, 0);
        }
    }

    // ---- epilogue: Y * inv-deg -> zb row tIdx (bf16, k=i*32+b, swizzled) ----
    {
        float inv = 1.f / fmaxf((float)deg, 1.f);
        unsigned rb = (unsigned)tIdx << 12;
        unsigned swz = (unsigned)((tIdx & 7) << 4);
#pragma unroll
        for (int q = 0; q < 4; ++q) {
            int i0 = (mh << 5) + (lk << 2) + q;          // m'=0
            int i1 = i0 + 16;                            // m'=1
            *(unsigned short*)(zb + rb + ((((unsigned)i0 << 6) + ((unsigned)l15 << 1)) ^ swz))        = f2bf(acc00[q] * inv);
            *(unsigned short*)(zb + rb + ((((unsigned)i0 << 6) + ((unsigned)(16 + l15) << 1)) ^ swz)) = f2bf(acc01[q] * inv);
            *(unsigned short*)(zb + rb + ((((unsigned)i1 << 6) + ((unsigned)l15 << 1)) ^ swz))        = f2bf(acc10[q] * inv);
            *(unsigned short*)(zb + rb + ((((unsigned)i1 << 6) + ((unsigned)(16 + l15) << 1)) ^ swz)) = f2bf(acc11[q] * inv);
        }
        if (lane < 32) {                                 // slot b=30: xself for i in wave's range
            unsigned by = (((unsigned)(((mh << 5) + lane) << 6)) + 60u) ^ swz;
            *(unsigned short*)(zb + rb + by) = f2bf(xself);
            if (mh == 0 && lane == 0)                    // slot b=31 @ i=0: 1.0 (bias hot-one)
                *(unsigned short*)(zb + rb + (62u ^ swz)) = (unsigned short)0x3F80;
        }
    }
    __syncthreads();

    // ---- phase 2: wave w -> colblk=w&3, K-half kq=w>>2 (1024 each, 32 steps) ----
    {
        int colblk = w & 3, kq = w >> 2;
        const __hip_bfloat16* bbase = bbT + (((size_t)(colblk * 16 + l15)) << 11) + (kq << 10) + (lk << 3);
        unsigned arow = (unsigned)(l15 & 3) << 12;
        unsigned aswz = (unsigned)((l15 & 3) << 4);
        f32x4 acc2 = {0.f,0.f,0.f,0.f};
#pragma unroll 4
        for (int s = 0; s < 32; ++s) {
            unsigned abyte = ((unsigned)((kq << 11) + (s << 6) + (lk << 4))) ^ aswz;
            short8v a = *(const short8v*)(zb + arow + abyte);
            short8v b = *(const short8v*)(bbase + (s << 5));
            acc2 = __builtin_amdgcn_mfma_f32_16x16x32_bf16(a, b, acc2, 0, 0, 0);
        }
#pragma unroll
        for (int q = 0; q < 4; ++q)                      // D: col=l15, row=lk*4+q (row%4 = target)
            pf[(w << 8) + ((lk << 2) + q) * 16 + l15] = acc2[q];
    }
    __syncthreads();

    // ---- reduce 2 K-halves + write (256 threads = 4 targets x 64 cols) ----
    if (tid < 256) {
        int r = tid >> 6, c = tid & 63;
        int cb = c >> 4, cl = c & 15;
        int tt = t0 + r;
        if (tt < N) {
            float v = pf[(cb << 8) + (r << 4) + cl]
                    + pf[((cb + 4) << 8) + (r << 4) + cl];
            out[((size_t)tt << 6) + c] = v;
        }
    }
}

extern "C" void kernel_launch(void* const* d_in, const int* in_sizes, int n_in,
                              void* d_out, int out_size, void* d_ws, size_t ws_size,
                              hipStream_t stream) {
    const float* x     = (const float*)d_in[0];
    const int*   eidx  = (const int*)d_in[1];   // (2, E)
    const int*   etype = (const int*)d_in[2];
    const float* basis = (const float*)d_in[4];
    const float* coeff = (const float*)d_in[5];
    const float* sw    = (const float*)d_in[6];
    const float* bias  = (const float*)d_in[7];

    const int E = in_sizes[1] / 2;
    const int N = out_size / OUT_F;
    const int NB = (N + 255) >> 8;
    const int* srcv = eidx;
    const int* tgtv = eidx + E;
    float* out = (float*)d_out;

    size_t p = 0;
    auto alloc = [&](size_t bytes) { size_t cur = p; p += (bytes + 255) & ~(size_t)255; return cur; };
    char* base = (char*)d_ws;
    __hip_bfloat16* bbT   = (__hip_bfloat16*)(base + alloc((size_t)OUT_F * KROW * 2));
    int*            gsum  = (int*)(base + alloc(256 * 4));
    int*            gexcl = (int*)(base + alloc((size_t)(NB + 1) * 4));
    int*            bcur  = (int*)(base + alloc((size_t)NB * 4));
    int*            off   = (int*)(base + alloc((size_t)(N + 1) * 4));
    unsigned*       ssr   = (unsigned*)(base + alloc((size_t)E * 4));
    unsigned*       ssr2  = (unsigned*)(base + alloc((size_t)E * 4));
    (void)ws_size;

    hipMemsetAsync(gsum, 0, 256 * 4, stream);

    k_bbt<<<(OUT_F * KROW + 255) / 256, 256, 0, stream>>>(basis, sw, bias, bbT);
    k_b1a<<<256, 256, 0, stream>>>(tgtv, gsum, E);
    k_scanB<<<1, 64, 0, stream>>>(gsum, gexcl, bcur, off, NB, N);
    k_b1<<<(E + B1CHUNK - 1) / B1CHUNK, 1024, 0, stream>>>(srcv, tgtv, etype, bcur, ssr, E);
    k_b2<<<NB, 256, 0, stream>>>(ssr, gexcl, off, ssr2, N);
    k_fused<<<(N + 3) / 4, 512, 0, stream>>>(x, ssr2, off, coeff, bbT, out, N);
}

// Round 4
// 263.884 us; speedup vs baseline: 1.5370x; 1.5370x over previous
//
#include <hip/hip_runtime.h>
#include <hip/hip_bf16.h>

#define IN_F   64
#define OUT_F  64
#define N_RELS 32
#define N_BAS  30
#define KROW   2048               // k = i*32 + b  (i feature 0..63, b slot 0..31)
#define B1CHUNK 8192

typedef __attribute__((ext_vector_type(8))) short short8v;
typedef __attribute__((ext_vector_type(8))) _Float16 half8v;
typedef __attribute__((ext_vector_type(4))) float f32x4;

__device__ __forceinline__ int dmin(int a, int b) { return a < b ? a : b; }
__device__ __forceinline__ unsigned short f2bf(float f) {
    __hip_bfloat16 h = __float2bfloat16(f);
    return *(unsigned short*)&h;
}

// ---------- K1: bbT[o][i*32+b] : b<30 -> basis[b][i][o], b==30 -> sw[i][o], b==31 -> (i==0)?bias[o]:0
__global__ void k_bbt(const float* __restrict__ basis, const float* __restrict__ sw,
                      const float* __restrict__ bias, __hip_bfloat16* __restrict__ bbT) {
    int idx = blockIdx.x * blockDim.x + threadIdx.x;
    if (idx >= OUT_F * KROW) return;
    int o = idx >> 11, k = idx & (KROW - 1);
    int i = k >> 5, b = k & 31;
    float v;
    if (b < N_BAS)      v = basis[((size_t)b * IN_F + i) * OUT_F + o];
    else if (b == 30)   v = sw[(size_t)i * OUT_F + o];
    else                v = (i == 0) ? bias[o] : 0.f;
    bbT[idx] = __float2bfloat16(v);
}

// ---------- K2: coarse histogram by tgt>>8 ----------
__global__ void __launch_bounds__(256)
k_b1a(const int* __restrict__ tgt, int* __restrict__ gsum, int E) {
    __shared__ int lh[256];
    int tid = threadIdx.x;
    lh[tid] = 0;
    __syncthreads();
    for (int i = blockIdx.x * blockDim.x + tid; i < E; i += gridDim.x * blockDim.x)
        atomicAdd(&lh[tgt[i] >> 8], 1);
    __syncthreads();
    if (lh[tid]) atomicAdd(&gsum[tid], lh[tid]);
}

// ---------- K3: tiny scan of coarse buckets ----------
__global__ void k_scanB(const int* __restrict__ gsum, int* __restrict__ gexcl,
                        int* __restrict__ bcur, int* __restrict__ off, int NB, int N) {
    int l = threadIdx.x;
    int a0 = (4*l+0 < NB) ? gsum[4*l+0] : 0;
    int a1 = (4*l+1 < NB) ? gsum[4*l+1] : 0;
    int a2 = (4*l+2 < NB) ? gsum[4*l+2] : 0;
    int a3 = (4*l+3 < NB) ? gsum[4*l+3] : 0;
    int s = a0 + a1 + a2 + a3;
    int sc = s;
    for (int d = 1; d < 64; d <<= 1) {
        int o = __shfl_up(sc, d, 64);
        if (l >= d) sc += o;
    }
    int base = sc - s;
    if (4*l+0 < NB) { gexcl[4*l+0] = base;          bcur[4*l+0] = base; }
    if (4*l+1 < NB) { gexcl[4*l+1] = base+a0;       bcur[4*l+1] = base+a0; }
    if (4*l+2 < NB) { gexcl[4*l+2] = base+a0+a1;    bcur[4*l+2] = base+a0+a1; }
    if (4*l+3 < NB) { gexcl[4*l+3] = base+a0+a1+a2; bcur[4*l+3] = base+a0+a1+a2; }
    if (l == 63) { gexcl[NB] = sc; off[N] = sc; }
}

// ---------- K4: coarse bucket scatter ----------
__global__ void __launch_bounds__(1024)
k_b1(const int* __restrict__ src, const int* __restrict__ tgt, const int* __restrict__ et,
     int* __restrict__ bcur, unsigned* __restrict__ ssr, int E) {
    __shared__ unsigned ls_p[B1CHUNK];
    __shared__ unsigned char ls_b[B1CHUNK];
    __shared__ int lh[256], lbase[256], gbase[256], lcur[256];
    int tid = threadIdx.x;
    int e0 = blockIdx.x * B1CHUNK;
    int n = E - e0; if (n > B1CHUNK) n = B1CHUNK;
    if (tid < 256) { lh[tid] = 0; lcur[tid] = 0; }
    __syncthreads();
    unsigned pr[8]; int br[8];
#pragma unroll
    for (int k = 0; k < 8; ++k) {
        int i = k * 1024 + tid;
        br[k] = -1;
        if (i < n) {
            int t = tgt[e0 + i];
            br[k] = t >> 8;
            pr[k] = ((unsigned)(t & 255) << 21) | ((unsigned)src[e0 + i] << 5) | (unsigned)et[e0 + i];
            atomicAdd(&lh[br[k]], 1);
        }
    }
    __syncthreads();
    if (tid < 64) {
        int a0 = lh[4*tid], a1 = lh[4*tid+1], a2 = lh[4*tid+2], a3 = lh[4*tid+3];
        int s = a0 + a1 + a2 + a3, sc = s;
        for (int d = 1; d < 64; d <<= 1) {
            int o = __shfl_up(sc, d, 64);
            if (tid >= d) sc += o;
        }
        int base = sc - s;
        lbase[4*tid] = base; lbase[4*tid+1] = base+a0;
        lbase[4*tid+2] = base+a0+a1; lbase[4*tid+3] = base+a0+a1+a2;
    }
    __syncthreads();
    if (tid < 256 && lh[tid]) gbase[tid] = atomicAdd(&bcur[tid], lh[tid]);
    __syncthreads();
#pragma unroll
    for (int k = 0; k < 8; ++k) {
        if (br[k] >= 0) {
            int pos = atomicAdd(&lcur[br[k]], 1);
            int s = lbase[br[k]] + pos;
            ls_p[s] = pr[k];
            ls_b[s] = (unsigned char)br[k];
        }
    }
    __syncthreads();
#pragma unroll
    for (int k = 0; k < 8; ++k) {
        int i = k * 1024 + tid;
        if (i < n) {
            int b = ls_b[i];
            ssr[gbase[b] + (i - lbase[b])] = ls_p[i];
        }
    }
}

// ---------- K5: per-bucket fine sort ----------
__global__ void __launch_bounds__(256)
k_b2(const unsigned* __restrict__ ssr, const int* __restrict__ gexcl,
     int* __restrict__ off, unsigned* __restrict__ ssr2, int N) {
    __shared__ int lh[256], lofs[256], lcur[256];
    int g = blockIdx.x, tid = threadIdx.x;
    int o0 = gexcl[g], o1 = gexcl[g + 1];
    lh[tid] = 0;
    __syncthreads();
    for (int i = o0 + tid; i < o1; i += 256)
        atomicAdd(&lh[ssr[i] >> 21], 1);
    __syncthreads();
    if (tid < 64) {
        int a0 = lh[4*tid], a1 = lh[4*tid+1], a2 = lh[4*tid+2], a3 = lh[4*tid+3];
        int s = a0 + a1 + a2 + a3, sc = s;
        for (int d = 1; d < 64; d <<= 1) {
            int o = __shfl_up(sc, d, 64);
            if (tid >= d) sc += o;
        }
        int base = sc - s;
        lofs[4*tid] = base; lofs[4*tid+1] = base+a0;
        lofs[4*tid+2] = base+a0+a1; lofs[4*tid+3] = base+a0+a1+a2;
    }
    __syncthreads();
    int t = (g << 8) + tid;
    if (t < N) off[t] = o0 + lofs[tid];
    lcur[tid] = o0 + lofs[tid];
    __syncthreads();
    for (int i = o0 + tid; i < o1; i += 256) {
        unsigned p = ssr[i];
        int pos = atomicAdd(&lcur[p >> 21], 1);
        ssr2[pos] = p;
    }
}

// ---------- K6: fused v7 — 8 targets/block, 1024 thr, 2 waves/target edge, 16-wave phase-2 ----------
// Edge GEMM per target: Y^T[i][b] = sum_e x[src_e][i]*coeff[r_e][b], mfma_f32_16x16x32_f16.
// Wave w: tIdx=w>>1 (0..7), mh=w&1 owns feats [mh*32, mh*32+32) -> 16 AGPR acc (low regs).
// Phase2 (R2 structure): 16 waves = 4 colblks x 4 K-quarters, 16 steps; A rows = l15&7
// (8 targets, dup x2). Reduce sums 4 K-quarters from dup copy 0. ~48KB LDS -> 2 blocks/CU.
__global__ void __launch_bounds__(1024, 8)
k_fused(const float* __restrict__ x, const unsigned* __restrict__ ssr2,
        const int* __restrict__ off, const float* __restrict__ coeff,
        const __hip_bfloat16* __restrict__ bbT, float* __restrict__ out, int N) {
    __shared__ __align__(16) unsigned char zb[8 * 4096];    // 8 targets x 2048 bf16, XOR-swizzled
    __shared__ __align__(16) float pf[16 * 256];            // phase-2 partials; head aliases cofs2
    unsigned* cofs2 = (unsigned*)pf;                        // [33][16] u32 {f16 c | f16 c+16}, row32=0
    int tid = threadIdx.x;
    int w = tid >> 6, lane = tid & 63;
    int tIdx = w >> 1, mh = w & 1;
    int t0 = blockIdx.x * 8;
    int t = t0 + tIdx;

    // hoisted loads (latency hides under coeff staging + barrier)
    int offt = 0, offt1 = 0;
    float xself = 0.f;
    if (t < N) {
        offt  = off[t];
        offt1 = off[t + 1];
        xself = x[((size_t)t << 6) + (mh << 5) + (lane & 31)];
    }

    // stage coeff pairs -> LDS
    for (int idx = tid; idx < 33 * 16; idx += 1024) {
        int r = idx >> 4, c = idx & 15;
        float lo = (r < 32) ? coeff[r * N_BAS + c] : 0.f;
        float hi = (r < 32 && (c + 16) < N_BAS) ? coeff[r * N_BAS + c + 16] : 0.f;
        _Float16 hl = (_Float16)lo, hh = (_Float16)hi;
        cofs2[idx] = (unsigned)*(unsigned short*)&hl | ((unsigned)*(unsigned short*)&hh << 16);
    }
    __syncthreads();

    int l15 = lane & 15, lk = lane >> 4;
    int vq = lk << 3;                      // edge-slot base of this quadrant
    int vperm = (lane & 48) << 1;          // bpermute byte base
    unsigned xadd = (unsigned)((mh << 7) + (l15 << 2));

    int s0 = __builtin_amdgcn_readfirstlane(offt);
    int s1 = __builtin_amdgcn_readfirstlane(offt1);
    int deg = (t < N) ? (s1 - s0) : 0;

    f32x4 acc00 = {0.f,0.f,0.f,0.f};
    f32x4 acc01 = acc00, acc10 = acc00, acc11 = acc00;

    if (deg > 0) {
        const char* xB = (const char*)x;
        int last = s1 - 1;
#pragma unroll 1
        for (int kt = 0; kt * 32 < deg; ++kt) {
            int base = s0 + kt * 32;
            unsigned ew = ssr2[dmin(base + (lane & 31), last)];
            int rem = deg - kt * 32;
            float xr0[8], xr1[8];
            unsigned bw[8];
#pragma unroll
            for (int j = 0; j < 8; ++j) {
                unsigned wj = (unsigned)__builtin_amdgcn_ds_bpermute(vperm + j * 4, (int)ew);
                unsigned xoff = (((wj >> 5) & 0xFFFFu) << 8) + xadd;
                unsigned rrow = ((vq + j) < rem) ? (wj & 31u) : 32u;   // pad -> zero row
                bw[j] = cofs2[(rrow << 4) + l15];
                xr0[j] = *(const float*)(xB + xoff);
                xr1[j] = *(const float*)(xB + xoff + 64);
            }
            union { unsigned short u[8]; half8v h; } bf0, bf1;
            union { _Float16 f[8]; half8v h; } a0, a1;
#pragma unroll
            for (int j = 0; j < 8; ++j) {
                bf0.u[j] = (unsigned short)(bw[j] & 0xFFFFu);
                bf1.u[j] = (unsigned short)(bw[j] >> 16);
                a0.f[j] = (_Float16)xr0[j];
                a1.f[j] = (_Float16)xr1[j];
            }
            acc00 = __builtin_amdgcn_mfma_f32_16x16x32_f16(a0.h, bf0.h, acc00, 0, 0, 0);
            acc01 = __builtin_amdgcn_mfma_f32_16x16x32_f16(a0.h, bf1.h, acc01, 0, 0, 0);
            acc10 = __builtin_amdgcn_mfma_f32_16x16x32_f16(a1.h, bf0.h, acc10, 0, 0, 0);
            acc11 = __builtin_amdgcn_mfma_f32_16x16x32_f16(a1.h, bf1.h, acc11, 0, 0, 0);
        }
    }

    // ---- epilogue: Y * inv-deg -> zb row tIdx (bf16, k=i*32+b, swizzled byte^=((row&7)<<4)) ----
    {
        float inv = 1.f / fmaxf((float)deg, 1.f);
        unsigned rb = (unsigned)tIdx << 12;
        unsigned swz = (unsigned)((tIdx & 7) << 4);
#pragma unroll
        for (int q = 0; q < 4; ++q) {
            int i0 = (mh << 5) + (lk << 2) + q;          // m'=0
            int i1 = i0 + 16;                            // m'=1
            *(unsigned short*)(zb + rb + ((((unsigned)i0 << 6) + ((unsigned)l15 << 1)) ^ swz))        = f2bf(acc00[q] * inv);
            *(unsigned short*)(zb + rb + ((((unsigned)i0 << 6) + ((unsigned)(16 + l15) << 1)) ^ swz)) = f2bf(acc01[q] * inv);
            *(unsigned short*)(zb + rb + ((((unsigned)i1 << 6) + ((unsigned)l15 << 1)) ^ swz))        = f2bf(acc10[q] * inv);
            *(unsigned short*)(zb + rb + ((((unsigned)i1 << 6) + ((unsigned)(16 + l15) << 1)) ^ swz)) = f2bf(acc11[q] * inv);
        }
        if (lane < 32) {                                 // slot b=30: xself for i in wave's range
            unsigned by = (((unsigned)(((mh << 5) + lane) << 6)) + 60u) ^ swz;
            *(unsigned short*)(zb + rb + by) = f2bf(xself);
            if (mh == 0 && lane == 0)                    // slot b=31 @ i=0: 1.0 (bias hot-one)
                *(unsigned short*)(zb + rb + (62u ^ swz)) = (unsigned short)0x3F80;
        }
    }
    __syncthreads();

    // ---- phase 2 (R2 structure): wave w -> colblk=w&3, K-quarter kq=w>>2 (512 each, 16 steps)
    {
        int colblk = w & 3, kq = w >> 2;
        const short8v* bp = (const short8v*)(bbT + (((size_t)(colblk * 16 + l15)) << 11) + (kq << 9) + lk * 8);
        unsigned arow = (unsigned)(l15 & 7) << 12;       // 8 targets, rows 8-15 duplicate
        unsigned aswz = (unsigned)((l15 & 7) << 4);
        f32x4 acc2 = {0.f,0.f,0.f,0.f};
#pragma unroll 4
        for (int s = 0; s < 16; ++s) {
            unsigned abyte = ((unsigned)((kq << 10) + (s << 6) + (lk << 4))) ^ aswz;
            short8v a = *(const short8v*)(zb + arow + abyte);
            short8v b = bp[s * 4];
            acc2 = __builtin_amdgcn_mfma_f32_16x16x32_bf16(a, b, acc2, 0, 0, 0);
        }
#pragma unroll
        for (int q = 0; q < 4; ++q)                      // D: col=l15, row=lk*4+q (row&7 = target)
            pf[(w << 8) + ((lk << 2) + q) * 16 + l15] = acc2[q];
    }
    __syncthreads();

    // ---- reduce 4 K-quarters + write (512 threads = 8 targets x 64 cols; dup copy 0 only)
    if (tid < 512) {
        int r = tid >> 6, c = tid & 63;                  // r = target 0..7 (D row r, not r+8)
        int cb = c >> 4, cl = c & 15;
        int tt = t0 + r;
        if (tt < N) {
            float v = pf[(((0 << 2) + cb) << 8) + (r << 4) + cl]
                    + pf[(((1 << 2) + cb) << 8) + (r << 4) + cl]
                    + pf[(((2 << 2) + cb) << 8) + (r << 4) + cl]
                    + pf[(((3 << 2) + cb) << 8) + (r << 4) + cl];
            out[((size_t)tt << 6) + c] = v;
        }
    }
}

extern "C" void kernel_launch(void* const* d_in, const int* in_sizes, int n_in,
                              void* d_out, int out_size, void* d_ws, size_t ws_size,
                              hipStream_t stream) {
    const float* x     = (const float*)d_in[0];
    const int*   eidx  = (const int*)d_in[1];   // (2, E)
    const int*   etype = (const int*)d_in[2];
    const float* basis = (const float*)d_in[4];
    const float* coeff = (const float*)d_in[5];
    const float* sw    = (const float*)d_in[6];
    const float* bias  = (const float*)d_in[7];

    const int E = in_sizes[1] / 2;
    const int N = out_size / OUT_F;
    const int NB = (N + 255) >> 8;
    const int* srcv = eidx;
    const int* tgtv = eidx + E;
    float* out = (float*)d_out;

    size_t p = 0;
    auto alloc = [&](size_t bytes) { size_t cur = p; p += (bytes + 255) & ~(size_t)255; return cur; };
    char* base = (char*)d_ws;
    __hip_bfloat16* bbT   = (__hip_bfloat16*)(base + alloc((size_t)OUT_F * KROW * 2));
    int*            gsum  = (int*)(base + alloc(256 * 4));
    int*            gexcl = (int*)(base + alloc((size_t)(NB + 1) * 4));
    int*            bcur  = (int*)(base + alloc((size_t)NB * 4));
    int*            off   = (int*)(base + alloc((size_t)(N + 1) * 4));
    unsigned*       ssr   = (unsigned*)(base + alloc((size_t)E * 4));
    unsigned*       ssr2  = (unsigned*)(base + alloc((size_t)E * 4));
    (void)ws_size;

    hipMemsetAsync(gsum, 0, 256 * 4, stream);

    k_bbt<<<(OUT_F * KROW + 255) / 256, 256, 0, stream>>>(basis, sw, bias, bbT);
    k_b1a<<<256, 256, 0, stream>>>(tgtv, gsum, E);
    k_scanB<<<1, 64, 0, stream>>>(gsum, gexcl, bcur, off, NB, N);
    k_b1<<<(E + B1CHUNK - 1) / B1CHUNK, 1024, 0, stream>>>(srcv, tgtv, etype, bcur, ssr, E);
    k_b2<<<NB, 256, 0, stream>>>(ssr, gexcl, off, ssr2, N);
    k_fused<<<(N + 7) / 8, 1024, 0, stream>>>(x, ssr2, off, coeff, bbT, out, N);
}

// Round 5
// 153.750 us; speedup vs baseline: 2.6380x; 1.7163x over previous
//
#include <hip/hip_runtime.h>
#include <hip/hip_bf16.h>

#define IN_F   64
#define OUT_F  64
#define N_RELS 32
#define N_BAS  30
#define KROW   2048               // k = i*32 + b  (i feature 0..63, b slot 0..31)
#define B1CHUNK 8192

typedef __attribute__((ext_vector_type(8))) short short8v;
typedef __attribute__((ext_vector_type(8))) _Float16 half8v;
typedef __attribute__((ext_vector_type(4))) float f32x4;

__device__ __forceinline__ int dmin(int a, int b) { return a < b ? a : b; }
__device__ __forceinline__ unsigned short f2bf(float f) {
    __hip_bfloat16 h = __float2bfloat16(f);
    return *(unsigned short*)&h;
}

// ---------- K1: bbT in PHASE-2 FRAGMENT ORDER: idx = [cb(4)][kq(4)][s(16)][lane(64)][e(8)]
// value = BB[k][o] with o = cb*16 + (lane&15), k = kq*512 + s*32 + (lane>>4)*8 + e,
// BB[k=i*32+b][o]: b<30 -> basis[b][i][o], b==30 -> sw[i][o], b==31 -> (i==0)?bias[o]:0
__global__ void k_bbt(const float* __restrict__ basis, const float* __restrict__ sw,
                      const float* __restrict__ bias, __hip_bfloat16* __restrict__ bbT) {
    int idx = blockIdx.x * blockDim.x + threadIdx.x;
    if (idx >= OUT_F * KROW) return;
    int e = idx & 7, lane = (idx >> 3) & 63, s = (idx >> 9) & 15, kq = (idx >> 13) & 3, cb = idx >> 15;
    int l15 = lane & 15, lk = lane >> 4;
    int o = cb * 16 + l15;
    int k = kq * 512 + s * 32 + lk * 8 + e;
    int i = k >> 5, b = k & 31;
    float v;
    if (b < N_BAS)      v = basis[((size_t)b * IN_F + i) * OUT_F + o];
    else if (b == 30)   v = sw[(size_t)i * OUT_F + o];
    else                v = (i == 0) ? bias[o] : 0.f;
    bbT[idx] = __float2bfloat16(v);
}

// ---------- K2: coarse histogram by tgt>>8 ----------
__global__ void __launch_bounds__(256)
k_b1a(const int* __restrict__ tgt, int* __restrict__ gsum, int E) {
    __shared__ int lh[256];
    int tid = threadIdx.x;
    lh[tid] = 0;
    __syncthreads();
    for (int i = blockIdx.x * blockDim.x + tid; i < E; i += gridDim.x * blockDim.x)
        atomicAdd(&lh[tgt[i] >> 8], 1);
    __syncthreads();
    if (lh[tid]) atomicAdd(&gsum[tid], lh[tid]);
}

// ---------- K3: tiny scan of coarse buckets ----------
__global__ void k_scanB(const int* __restrict__ gsum, int* __restrict__ gexcl,
                        int* __restrict__ bcur, int* __restrict__ off, int NB, int N) {
    int l = threadIdx.x;
    int a0 = (4*l+0 < NB) ? gsum[4*l+0] : 0;
    int a1 = (4*l+1 < NB) ? gsum[4*l+1] : 0;
    int a2 = (4*l+2 < NB) ? gsum[4*l+2] : 0;
    int a3 = (4*l+3 < NB) ? gsum[4*l+3] : 0;
    int s = a0 + a1 + a2 + a3;
    int sc = s;
    for (int d = 1; d < 64; d <<= 1) {
        int o = __shfl_up(sc, d, 64);
        if (l >= d) sc += o;
    }
    int base = sc - s;
    if (4*l+0 < NB) { gexcl[4*l+0] = base;          bcur[4*l+0] = base; }
    if (4*l+1 < NB) { gexcl[4*l+1] = base+a0;       bcur[4*l+1] = base+a0; }
    if (4*l+2 < NB) { gexcl[4*l+2] = base+a0+a1;    bcur[4*l+2] = base+a0+a1; }
    if (4*l+3 < NB) { gexcl[4*l+3] = base+a0+a1+a2; bcur[4*l+3] = base+a0+a1+a2; }
    if (l == 63) { gexcl[NB] = sc; off[N] = sc; }
}

// ---------- K4: coarse bucket scatter ----------
__global__ void __launch_bounds__(1024)
k_b1(const int* __restrict__ src, const int* __restrict__ tgt, const int* __restrict__ et,
     int* __restrict__ bcur, unsigned* __restrict__ ssr, int E) {
    __shared__ unsigned ls_p[B1CHUNK];
    __shared__ unsigned char ls_b[B1CHUNK];
    __shared__ int lh[256], lbase[256], gbase[256], lcur[256];
    int tid = threadIdx.x;
    int e0 = blockIdx.x * B1CHUNK;
    int n = E - e0; if (n > B1CHUNK) n = B1CHUNK;
    if (tid < 256) { lh[tid] = 0; lcur[tid] = 0; }
    __syncthreads();
    unsigned pr[8]; int br[8];
#pragma unroll
    for (int k = 0; k < 8; ++k) {
        int i = k * 1024 + tid;
        br[k] = -1;
        if (i < n) {
            int t = tgt[e0 + i];
            br[k] = t >> 8;
            pr[k] = ((unsigned)(t & 255) << 21) | ((unsigned)src[e0 + i] << 5) | (unsigned)et[e0 + i];
            atomicAdd(&lh[br[k]], 1);
        }
    }
    __syncthreads();
    if (tid < 64) {
        int a0 = lh[4*tid], a1 = lh[4*tid+1], a2 = lh[4*tid+2], a3 = lh[4*tid+3];
        int s = a0 + a1 + a2 + a3, sc = s;
        for (int d = 1; d < 64; d <<= 1) {
            int o = __shfl_up(sc, d, 64);
            if (tid >= d) sc += o;
        }
        int base = sc - s;
        lbase[4*tid] = base; lbase[4*tid+1] = base+a0;
        lbase[4*tid+2] = base+a0+a1; lbase[4*tid+3] = base+a0+a1+a2;
    }
    __syncthreads();
    if (tid < 256 && lh[tid]) gbase[tid] = atomicAdd(&bcur[tid], lh[tid]);
    __syncthreads();
#pragma unroll
    for (int k = 0; k < 8; ++k) {
        if (br[k] >= 0) {
            int pos = atomicAdd(&lcur[br[k]], 1);
            int s = lbase[br[k]] + pos;
            ls_p[s] = pr[k];
            ls_b[s] = (unsigned char)br[k];
        }
    }
    __syncthreads();
#pragma unroll
    for (int k = 0; k < 8; ++k) {
        int i = k * 1024 + tid;
        if (i < n) {
            int b = ls_b[i];
            ssr[gbase[b] + (i - lbase[b])] = ls_p[i];
        }
    }
}

// ---------- K5: per-bucket fine sort ----------
__global__ void __launch_bounds__(256)
k_b2(const unsigned* __restrict__ ssr, const int* __restrict__ gexcl,
     int* __restrict__ off, unsigned* __restrict__ ssr2, int N) {
    __shared__ int lh[256], lofs[256], lcur[256];
    int g = blockIdx.x, tid = threadIdx.x;
    int o0 = gexcl[g], o1 = gexcl[g + 1];
    lh[tid] = 0;
    __syncthreads();
    for (int i = o0 + tid; i < o1; i += 256)
        atomicAdd(&lh[ssr[i] >> 21], 1);
    __syncthreads();
    if (tid < 64) {
        int a0 = lh[4*tid], a1 = lh[4*tid+1], a2 = lh[4*tid+2], a3 = lh[4*tid+3];
        int s = a0 + a1 + a2 + a3, sc = s;
        for (int d = 1; d < 64; d <<= 1) {
            int o = __shfl_up(sc, d, 64);
            if (tid >= d) sc += o;
        }
        int base = sc - s;
        lofs[4*tid] = base; lofs[4*tid+1] = base+a0;
        lofs[4*tid+2] = base+a0+a1; lofs[4*tid+3] = base+a0+a1+a2;
    }
    __syncthreads();
    int t = (g << 8) + tid;
    if (t < N) off[t] = o0 + lofs[tid];
    lcur[tid] = o0 + lofs[tid];
    __syncthreads();
    for (int i = o0 + tid; i < o1; i += 256) {
        unsigned p = ssr[i];
        int pos = atomicAdd(&lcur[p >> 21], 1);
        ssr2[pos] = p;
    }
}

// ---------- K6: fused v8 — 16 targets/block, 2-round edge (2 waves/target/round), coalesced phase-2 B ----------
// Edge GEMM per target: Y^T[i][b] = sum_e x[src_e][i]*coeff[r_e][b], mfma_f32_16x16x32_f16.
// Round r: wave w handles target tIdx = (w>>1) + r*8, mh=w&1 owns feats [mh*32,+32) (16 AGPR acc).
// Phase2 (R2 structure, 16 unique targets): 16 waves = 4 colblks x 4 K-quarters, 16 steps;
// B from fragment-ordered bbT -> per-step contiguous 1KB coalesced load. LDS 80KB -> 2 blocks/CU.
__global__ void __launch_bounds__(1024, 8)
k_fused(const float* __restrict__ x, const unsigned* __restrict__ ssr2,
        const int* __restrict__ off, const float* __restrict__ coeff,
        const __hip_bfloat16* __restrict__ bbT, float* __restrict__ out, int N) {
    __shared__ __align__(16) unsigned char zb[16 * 4096];   // 16 targets x 2048 bf16, XOR-swizzled
    __shared__ __align__(16) float pf[16 * 256];            // phase-2 partials; head aliases cofs2
    unsigned* cofs2 = (unsigned*)pf;                        // [33][16] u32 {f16 c | f16 c+16}, row32=0
    int tid = threadIdx.x;
    int w = tid >> 6, lane = tid & 63;
    int mh = w & 1;
    int t0 = blockIdx.x * 16;

    // hoisted per-round loads (latency hides under coeff staging + barrier)
    int offv[2], offv1[2];
    float xs[2];
#pragma unroll
    for (int r = 0; r < 2; ++r) {
        int tt = t0 + (w >> 1) + (r << 3);
        int ok = (tt < N);
        offv[r]  = ok ? off[tt] : 0;
        offv1[r] = ok ? off[tt + 1] : 0;
        xs[r]    = ok ? x[((size_t)tt << 6) + (mh << 5) + (lane & 31)] : 0.f;
    }

    // stage coeff pairs -> LDS
    for (int idx = tid; idx < 33 * 16; idx += 1024) {
        int r = idx >> 4, c = idx & 15;
        float lo = (r < 32) ? coeff[r * N_BAS + c] : 0.f;
        float hi = (r < 32 && (c + 16) < N_BAS) ? coeff[r * N_BAS + c + 16] : 0.f;
        _Float16 hl = (_Float16)lo, hh = (_Float16)hi;
        cofs2[idx] = (unsigned)*(unsigned short*)&hl | ((unsigned)*(unsigned short*)&hh << 16);
    }
    __syncthreads();

    int l15 = lane & 15, lk = lane >> 4;
    int vq = lk << 3;                      // edge-slot base of this quadrant
    int vperm = (lane & 48) << 1;          // bpermute byte base
    unsigned xadd = (unsigned)((mh << 7) + (l15 << 2));
    const char* xB = (const char*)x;

#pragma unroll 1
    for (int rnd = 0; rnd < 2; ++rnd) {
        int tIdx = (w >> 1) + (rnd << 3);
        int s0 = __builtin_amdgcn_readfirstlane(offv[rnd]);
        int s1 = __builtin_amdgcn_readfirstlane(offv1[rnd]);
        int deg = s1 - s0;

        f32x4 acc00 = {0.f,0.f,0.f,0.f};
        f32x4 acc01 = acc00, acc10 = acc00, acc11 = acc00;

        if (deg > 0) {
            int last = s1 - 1;
#pragma unroll 1
            for (int kt = 0; kt * 32 < deg; ++kt) {
                int base = s0 + kt * 32;
                unsigned ew = ssr2[dmin(base + (lane & 31), last)];
                int rem = deg - kt * 32;
                float xr0[8], xr1[8];
                unsigned bw[8];
#pragma unroll
                for (int j = 0; j < 8; ++j) {
                    unsigned wj = (unsigned)__builtin_amdgcn_ds_bpermute(vperm + j * 4, (int)ew);
                    unsigned xoff = (((wj >> 5) & 0xFFFFu) << 8) + xadd;
                    unsigned rrow = ((vq + j) < rem) ? (wj & 31u) : 32u;   // pad -> zero row
                    bw[j] = cofs2[(rrow << 4) + l15];
                    xr0[j] = *(const float*)(xB + xoff);
                    xr1[j] = *(const float*)(xB + xoff + 64);
                }
                union { unsigned short u[8]; half8v h; } bf0, bf1;
                union { _Float16 f[8]; half8v h; } a0, a1;
#pragma unroll
                for (int j = 0; j < 8; ++j) {
                    bf0.u[j] = (unsigned short)(bw[j] & 0xFFFFu);
                    bf1.u[j] = (unsigned short)(bw[j] >> 16);
                    a0.f[j] = (_Float16)xr0[j];
                    a1.f[j] = (_Float16)xr1[j];
                }
                acc00 = __builtin_amdgcn_mfma_f32_16x16x32_f16(a0.h, bf0.h, acc00, 0, 0, 0);
                acc01 = __builtin_amdgcn_mfma_f32_16x16x32_f16(a0.h, bf1.h, acc01, 0, 0, 0);
                acc10 = __builtin_amdgcn_mfma_f32_16x16x32_f16(a1.h, bf0.h, acc10, 0, 0, 0);
                acc11 = __builtin_amdgcn_mfma_f32_16x16x32_f16(a1.h, bf1.h, acc11, 0, 0, 0);
            }
        }

        // epilogue: Y * inv-deg -> zb row tIdx (bf16, k=i*32+b, swizzled byte^=((row&7)<<4))
        float inv = 1.f / fmaxf((float)deg, 1.f);
        unsigned rb = (unsigned)tIdx << 12;
        unsigned swz = (unsigned)((tIdx & 7) << 4);
#pragma unroll
        for (int q = 0; q < 4; ++q) {
            int i0 = (mh << 5) + (lk << 2) + q;          // m'=0
            int i1 = i0 + 16;                            // m'=1
            *(unsigned short*)(zb + rb + ((((unsigned)i0 << 6) + ((unsigned)l15 << 1)) ^ swz))        = f2bf(acc00[q] * inv);
            *(unsigned short*)(zb + rb + ((((unsigned)i0 << 6) + ((unsigned)(16 + l15) << 1)) ^ swz)) = f2bf(acc01[q] * inv);
            *(unsigned short*)(zb + rb + ((((unsigned)i1 << 6) + ((unsigned)l15 << 1)) ^ swz))        = f2bf(acc10[q] * inv);
            *(unsigned short*)(zb + rb + ((((unsigned)i1 << 6) + ((unsigned)(16 + l15) << 1)) ^ swz)) = f2bf(acc11[q] * inv);
        }
        if (lane < 32) {                                 // slot b=30: xself for i in wave's range
            unsigned by = (((unsigned)(((mh << 5) + lane) << 6)) + 60u) ^ swz;
            *(unsigned short*)(zb + rb + by) = f2bf(xs[rnd]);
            if (mh == 0 && lane == 0)                    // slot b=31 @ i=0: 1.0 (bias hot-one)
                *(unsigned short*)(zb + rb + (62u ^ swz)) = (unsigned short)0x3F80;
        }
    }
    __syncthreads();

    // ---- phase 2: wave w -> colblk=w&3, K-quarter kq=w>>2 (512 each, 16 steps);
    //      B loads contiguous 1KB/step from fragment-ordered bbT
    {
        int colblk = w & 3, kq = w >> 2;
        const char* bp2 = (const char*)bbT + (((unsigned)(colblk * 4 + kq)) << 14) + ((unsigned)lane << 4);
        unsigned arow = (unsigned)l15 << 12;
        unsigned aswz = (unsigned)((l15 & 7) << 4);
        f32x4 acc2 = {0.f,0.f,0.f,0.f};
#pragma unroll 4
        for (int s = 0; s < 16; ++s) {
            unsigned abyte = ((unsigned)((kq << 10) + (s << 6) + (lk << 4))) ^ aswz;
            short8v a = *(const short8v*)(zb + arow + abyte);
            short8v b = *(const short8v*)(bp2 + (s << 10));
            acc2 = __builtin_amdgcn_mfma_f32_16x16x32_bf16(a, b, acc2, 0, 0, 0);
        }
#pragma unroll
        for (int q = 0; q < 4; ++q)                      // D: col=l15, row=lk*4+q (row = target)
            pf[(w << 8) + ((lk << 2) + q) * 16 + l15] = acc2[q];
    }
    __syncthreads();

    // ---- reduce 4 K-quarters + write (1024 threads = 16 targets x 64 cols)
    {
        int row = w, col = lane;
        int cb = col >> 4, cl = col & 15;
        int tt = t0 + row;
        if (tt < N) {
            float v = pf[(((0 << 2) + cb) << 8) + (row << 4) + cl]
                    + pf[(((1 << 2) + cb) << 8) + (row << 4) + cl]
                    + pf[(((2 << 2) + cb) << 8) + (row << 4) + cl]
                    + pf[(((3 << 2) + cb) << 8) + (row << 4) + cl];
            out[((size_t)tt << 6) + col] = v;
        }
    }
}

extern "C" void kernel_launch(void* const* d_in, const int* in_sizes, int n_in,
                              void* d_out, int out_size, void* d_ws, size_t ws_size,
                              hipStream_t stream) {
    const float* x     = (const float*)d_in[0];
    const int*   eidx  = (const int*)d_in[1];   // (2, E)
    const int*   etype = (const int*)d_in[2];
    const float* basis = (const float*)d_in[4];
    const float* coeff = (const float*)d_in[5];
    const float* sw    = (const float*)d_in[6];
    const float* bias  = (const float*)d_in[7];

    const int E = in_sizes[1] / 2;
    const int N = out_size / OUT_F;
    const int NB = (N + 255) >> 8;
    const int* srcv = eidx;
    const int* tgtv = eidx + E;
    float* out = (float*)d_out;

    size_t p = 0;
    auto alloc = [&](size_t bytes) { size_t cur = p; p += (bytes + 255) & ~(size_t)255; return cur; };
    char* base = (char*)d_ws;
    __hip_bfloat16* bbT   = (__hip_bfloat16*)(base + alloc((size_t)OUT_F * KROW * 2));
    int*            gsum  = (int*)(base + alloc(256 * 4));
    int*            gexcl = (int*)(base + alloc((size_t)(NB + 1) * 4));
    int*            bcur  = (int*)(base + alloc((size_t)NB * 4));
    int*            off   = (int*)(base + alloc((size_t)(N + 1) * 4));
    unsigned*       ssr   = (unsigned*)(base + alloc((size_t)E * 4));
    unsigned*       ssr2  = (unsigned*)(base + alloc((size_t)E * 4));
    (void)ws_size;

    hipMemsetAsync(gsum, 0, 256 * 4, stream);

    k_bbt<<<(OUT_F * KROW + 255) / 256, 256, 0, stream>>>(basis, sw, bias, bbT);
    k_b1a<<<256, 256, 0, stream>>>(tgtv, gsum, E);
    k_scanB<<<1, 64, 0, stream>>>(gsum, gexcl, bcur, off, NB, N);
    k_b1<<<(E + B1CHUNK - 1) / B1CHUNK, 1024, 0, stream>>>(srcv, tgtv, etype, bcur, ssr, E);
    k_b2<<<NB, 256, 0, stream>>>(ssr, gexcl, off, ssr2, N);
    k_fused<<<(N + 15) / 16, 1024, 0, stream>>>(x, ssr2, off, coeff, bbT, out, N);
}

// Round 6
// 129.679 us; speedup vs baseline: 3.1277x; 1.1856x over previous
//
#include <hip/hip_runtime.h>
#include <hip/hip_bf16.h>

#define IN_F   64
#define OUT_F  64
#define N_RELS 32
#define N_BAS  30
#define KROW   2048               // k = i*32 + b  (i feature 0..63, b slot 0..31)
#define B1CHUNK 8192
#define ESTCAP 2048               // staged edge words per block (8 KB)

typedef __attribute__((ext_vector_type(8))) short short8v;
typedef __attribute__((ext_vector_type(8))) _Float16 half8v;
typedef __attribute__((ext_vector_type(4))) float f32x4;

__device__ __forceinline__ int dmin(int a, int b) { return a < b ? a : b; }
__device__ __forceinline__ unsigned short f2bf(float f) {
    __hip_bfloat16 h = __float2bfloat16(f);
    return *(unsigned short*)&h;
}

// ---------- K1: bbT in PHASE-2 FRAGMENT ORDER: idx = [cb(4)][kq(4)][s(16)][lane(64)][e(8)]
// value = BB[k][o] with o = cb*16 + (lane&15), k = kq*512 + s*32 + (lane>>4)*8 + e,
// BB[k=i*32+b][o]: b<30 -> basis[b][i][o], b==30 -> sw[i][o], b==31 -> (i==0)?bias[o]:0
__global__ void k_bbt(const float* __restrict__ basis, const float* __restrict__ sw,
                      const float* __restrict__ bias, __hip_bfloat16* __restrict__ bbT) {
    int idx = blockIdx.x * blockDim.x + threadIdx.x;
    if (idx >= OUT_F * KROW) return;
    int e = idx & 7, lane = (idx >> 3) & 63, s = (idx >> 9) & 15, kq = (idx >> 13) & 3, cb = idx >> 15;
    int l15 = lane & 15, lk = lane >> 4;
    int o = cb * 16 + l15;
    int k = kq * 512 + s * 32 + lk * 8 + e;
    int i = k >> 5, b = k & 31;
    float v;
    if (b < N_BAS)      v = basis[((size_t)b * IN_F + i) * OUT_F + o];
    else if (b == 30)   v = sw[(size_t)i * OUT_F + o];
    else                v = (i == 0) ? bias[o] : 0.f;
    bbT[idx] = __float2bfloat16(v);
}

// ---------- K1b: pack x rows to f16 pairs: xh[n][g] = {f16 x[n][f], f16 x[n][f+16]},
// f = (g&15) + (g>>4)*32.  (mh,l15) reads g = mh*16+l15 -> feats (mh*32+l15, mh*32+l15+16)
__global__ void k_xpack(const float* __restrict__ x, unsigned* __restrict__ xh, int N) {
    int idx = blockIdx.x * blockDim.x + threadIdx.x;
    if (idx >= N * 32) return;
    int g = idx & 31, n = idx >> 5;
    int f = (g & 15) + ((g >> 4) << 5);
    _Float16 lo = (_Float16)x[((size_t)n << 6) + f];
    _Float16 hi = (_Float16)x[((size_t)n << 6) + f + 16];
    xh[idx] = (unsigned)*(unsigned short*)&lo | ((unsigned)*(unsigned short*)&hi << 16);
}

// ---------- K2: coarse histogram by tgt>>8 ----------
__global__ void __launch_bounds__(256)
k_b1a(const int* __restrict__ tgt, int* __restrict__ gsum, int E) {
    __shared__ int lh[256];
    int tid = threadIdx.x;
    lh[tid] = 0;
    __syncthreads();
    for (int i = blockIdx.x * blockDim.x + tid; i < E; i += gridDim.x * blockDim.x)
        atomicAdd(&lh[tgt[i] >> 8], 1);
    __syncthreads();
    if (lh[tid]) atomicAdd(&gsum[tid], lh[tid]);
}

// ---------- K3: tiny scan of coarse buckets ----------
__global__ void k_scanB(const int* __restrict__ gsum, int* __restrict__ gexcl,
                        int* __restrict__ bcur, int* __restrict__ off, int NB, int N) {
    int l = threadIdx.x;
    int a0 = (4*l+0 < NB) ? gsum[4*l+0] : 0;
    int a1 = (4*l+1 < NB) ? gsum[4*l+1] : 0;
    int a2 = (4*l+2 < NB) ? gsum[4*l+2] : 0;
    int a3 = (4*l+3 < NB) ? gsum[4*l+3] : 0;
    int s = a0 + a1 + a2 + a3;
    int sc = s;
    for (int d = 1; d < 64; d <<= 1) {
        int o = __shfl_up(sc, d, 64);
        if (l >= d) sc += o;
    }
    int base = sc - s;
    if (4*l+0 < NB) { gexcl[4*l+0] = base;          bcur[4*l+0] = base; }
    if (4*l+1 < NB) { gexcl[4*l+1] = base+a0;       bcur[4*l+1] = base+a0; }
    if (4*l+2 < NB) { gexcl[4*l+2] = base+a0+a1;    bcur[4*l+2] = base+a0+a1; }
    if (4*l+3 < NB) { gexcl[4*l+3] = base+a0+a1+a2; bcur[4*l+3] = base+a0+a1+a2; }
    if (l == 63) { gexcl[NB] = sc; off[N] = sc; }
}

// ---------- K4: coarse bucket scatter ----------
__global__ void __launch_bounds__(1024)
k_b1(const int* __restrict__ src, const int* __restrict__ tgt, const int* __restrict__ et,
     int* __restrict__ bcur, unsigned* __restrict__ ssr, int E) {
    __shared__ unsigned ls_p[B1CHUNK];
    __shared__ unsigned char ls_b[B1CHUNK];
    __shared__ int lh[256], lbase[256], gbase[256], lcur[256];
    int tid = threadIdx.x;
    int e0 = blockIdx.x * B1CHUNK;
    int n = E - e0; if (n > B1CHUNK) n = B1CHUNK;
    if (tid < 256) { lh[tid] = 0; lcur[tid] = 0; }
    __syncthreads();
    unsigned pr[8]; int br[8];
#pragma unroll
    for (int k = 0; k < 8; ++k) {
        int i = k * 1024 + tid;
        br[k] = -1;
        if (i < n) {
            int t = tgt[e0 + i];
            br[k] = t >> 8;
            pr[k] = ((unsigned)(t & 255) << 21) | ((unsigned)src[e0 + i] << 5) | (unsigned)et[e0 + i];
            atomicAdd(&lh[br[k]], 1);
        }
    }
    __syncthreads();
    if (tid < 64) {
        int a0 = lh[4*tid], a1 = lh[4*tid+1], a2 = lh[4*tid+2], a3 = lh[4*tid+3];
        int s = a0 + a1 + a2 + a3, sc = s;
        for (int d = 1; d < 64; d <<= 1) {
            int o = __shfl_up(sc, d, 64);
            if (tid >= d) sc += o;
        }
        int base = sc - s;
        lbase[4*tid] = base; lbase[4*tid+1] = base+a0;
        lbase[4*tid+2] = base+a0+a1; lbase[4*tid+3] = base+a0+a1+a2;
    }
    __syncthreads();
    if (tid < 256 && lh[tid]) gbase[tid] = atomicAdd(&bcur[tid], lh[tid]);
    __syncthreads();
#pragma unroll
    for (int k = 0; k < 8; ++k) {
        if (br[k] >= 0) {
            int pos = atomicAdd(&lcur[br[k]], 1);
            int s = lbase[br[k]] + pos;
            ls_p[s] = pr[k];
            ls_b[s] = (unsigned char)br[k];
        }
    }
    __syncthreads();
#pragma unroll
    for (int k = 0; k < 8; ++k) {
        int i = k * 1024 + tid;
        if (i < n) {
            int b = ls_b[i];
            ssr[gbase[b] + (i - lbase[b])] = ls_p[i];
        }
    }
}

// ---------- K5: per-bucket fine sort ----------
__global__ void __launch_bounds__(256)
k_b2(const unsigned* __restrict__ ssr, const int* __restrict__ gexcl,
     int* __restrict__ off, unsigned* __restrict__ ssr2, int N) {
    __shared__ int lh[256], lofs[256], lcur[256];
    int g = blockIdx.x, tid = threadIdx.x;
    int o0 = gexcl[g], o1 = gexcl[g + 1];
    lh[tid] = 0;
    __syncthreads();
    for (int i = o0 + tid; i < o1; i += 256)
        atomicAdd(&lh[ssr[i] >> 21], 1);
    __syncthreads();
    if (tid < 64) {
        int a0 = lh[4*tid], a1 = lh[4*tid+1], a2 = lh[4*tid+2], a3 = lh[4*tid+3];
        int s = a0 + a1 + a2 + a3, sc = s;
        for (int d = 1; d < 64; d <<= 1) {
            int o = __shfl_up(sc, d, 64);
            if (tid >= d) sc += o;
        }
        int base = sc - s;
        lofs[4*tid] = base; lofs[4*tid+1] = base+a0;
        lofs[4*tid+2] = base+a0+a1; lofs[4*tid+3] = base+a0+a1+a2;
    }
    __syncthreads();
    int t = (g << 8) + tid;
    if (t < N) off[t] = o0 + lofs[tid];
    lcur[tid] = o0 + lofs[tid];
    __syncthreads();
    for (int i = o0 + tid; i < o1; i += 256) {
        unsigned p = ssr[i];
        int pos = atomicAdd(&lcur[p >> 21], 1);
        ssr2[pos] = p;
    }
}

// ---------- K6: fused v9 — LDS edge staging, f16-packed x gathers (1 load/edge/lane), no scratch ----------
// Edge GEMM per target: Y^T[i][b] = sum_e x[src_e][i]*coeff[r_e][b], mfma_f32_16x16x32_f16.
// Two rounds: wave w handles targets (w>>1) and (w>>1)+8; mh=w&1 owns feats [mh*32,+32).
// Block's edge words (contiguous in ssr2) staged to LDS (<=2048; global fallback beyond).
// Phase2 (verified R5 code): 16 waves = 4 colblks x 4 K-quarters; coalesced fragment-ordered bbT.
__global__ void __launch_bounds__(1024, 8)
k_fused(const float* __restrict__ x, const unsigned* __restrict__ xh,
        const unsigned* __restrict__ ssr2, const int* __restrict__ off,
        const float* __restrict__ coeff, const __hip_bfloat16* __restrict__ bbT,
        float* __restrict__ out, int N) {
    __shared__ __align__(16) unsigned char zb[16 * 4096];   // 16 targets x 2048 bf16, XOR-swizzled
    __shared__ __align__(16) float pf[16 * 256];            // phase-2 partials; head aliases cofs2+est
    unsigned* cofs2 = (unsigned*)pf;                        // [33][16] u32 {f16 c | f16 c+16}, row32=0
    unsigned* est   = ((unsigned*)pf) + 640;                // staged edge words (byte 2560..10751)
    int tid = threadIdx.x;
    int w = tid >> 6, lane = tid & 63;
    int mh = w & 1;
    int t0 = blockIdx.x * 16;

    // hoisted per-round loads (scalars, no arrays -> no scratch)
    int tA = t0 + (w >> 1), tB = tA + 8;
    int okA = (tA < N), okB = (tB < N);
    int offA0 = okA ? off[tA] : 0;
    int offA1 = okA ? off[tA + 1] : 0;
    int offB0 = okB ? off[tB] : 0;
    int offB1 = okB ? off[tB + 1] : 0;
    float xsA = okA ? x[((size_t)tA << 6) + (mh << 5) + (lane & 31)] : 0.f;
    float xsB = okB ? x[((size_t)tB << 6) + (mh << 5) + (lane & 31)] : 0.f;

    // block edge range (contiguous in ssr2)
    int bs0 = off[t0];
    int bse = off[dmin(t0 + 16, N)];
    int stage_n = dmin(bse - bs0, ESTCAP);

    // stage coeff pairs + edge words -> LDS
    for (int idx = tid; idx < 33 * 16; idx += 1024) {
        int r = idx >> 4, c = idx & 15;
        float lo = (r < 32) ? coeff[r * N_BAS + c] : 0.f;
        float hi = (r < 32 && (c + 16) < N_BAS) ? coeff[r * N_BAS + c + 16] : 0.f;
        _Float16 hl = (_Float16)lo, hh = (_Float16)hi;
        cofs2[idx] = (unsigned)*(unsigned short*)&hl | ((unsigned)*(unsigned short*)&hh << 16);
    }
    for (int i = tid; i < stage_n; i += 1024)
        est[i] = ssr2[bs0 + i];
    __syncthreads();

    int l15 = lane & 15, lk = lane >> 4;
    int vq = lk << 3;                      // edge-slot base of this quadrant
    int vperm = (lane & 48) << 1;          // bpermute byte base (fallback path)
    unsigned xadd2 = (unsigned)(((mh << 4) + l15) << 2);   // xh entry g = mh*16+l15, bytes
    const char* xhB = (const char*)xh;

    auto do_round = [&](int tIdx, int s0r, int s1r, float xselfv) {
        int deg = s1r - s0r;
        f32x4 acc00 = {0.f,0.f,0.f,0.f};
        f32x4 acc01 = acc00, acc10 = acc00, acc11 = acc00;
        if (deg > 0) {
            int last = s1r - 1;
            int locLast = last - bs0;
            bool staged = (locLast < stage_n);     // wave-uniform
#pragma unroll 1
            for (int kt = 0; kt * 32 < deg; ++kt) {
                int rem = deg - kt * 32;
                unsigned wjv[8];
                if (staged) {
                    int locb = (s0r - bs0) + kt * 32 + vq;
#pragma unroll
                    for (int j = 0; j < 8; ++j)
                        wjv[j] = est[dmin(locb + j, locLast)];      // broadcast ds_read
                } else {
                    unsigned ew = ssr2[dmin(s0r + kt * 32 + (lane & 31), last)];
#pragma unroll
                    for (int j = 0; j < 8; ++j)
                        wjv[j] = (unsigned)__builtin_amdgcn_ds_bpermute(vperm + j * 4, (int)ew);
                }
                union { unsigned short u[8]; half8v h; } bf0, bf1, a0, a1;
#pragma unroll
                for (int j = 0; j < 8; ++j) {
                    unsigned wj = wjv[j];
                    unsigned rrow = ((vq + j) < rem) ? (wj & 31u) : 32u;  // pad -> zero row
                    unsigned bw = cofs2[(rrow << 4) + l15];
                    unsigned xw = *(const unsigned*)(xhB + (((size_t)((wj >> 5) & 0xFFFFu)) << 7) + xadd2);
                    bf0.u[j] = (unsigned short)(bw & 0xFFFFu);
                    bf1.u[j] = (unsigned short)(bw >> 16);
                    a0.u[j]  = (unsigned short)(xw & 0xFFFFu);
                    a1.u[j]  = (unsigned short)(xw >> 16);
                }
                acc00 = __builtin_amdgcn_mfma_f32_16x16x32_f16(a0.h, bf0.h, acc00, 0, 0, 0);
                acc01 = __builtin_amdgcn_mfma_f32_16x16x32_f16(a0.h, bf1.h, acc01, 0, 0, 0);
                acc10 = __builtin_amdgcn_mfma_f32_16x16x32_f16(a1.h, bf0.h, acc10, 0, 0, 0);
                acc11 = __builtin_amdgcn_mfma_f32_16x16x32_f16(a1.h, bf1.h, acc11, 0, 0, 0);
            }
        }
        // epilogue: Y * inv-deg -> zb row tIdx (bf16, k=i*32+b, swizzled byte^=((row&7)<<4))
        float inv = 1.f / fmaxf((float)deg, 1.f);
        unsigned rb = (unsigned)tIdx << 12;
        unsigned swz = (unsigned)((tIdx & 7) << 4);
#pragma unroll
        for (int q = 0; q < 4; ++q) {
            int i0 = (mh << 5) + (lk << 2) + q;          // m'=0
            int i1 = i0 + 16;                            // m'=1
            *(unsigned short*)(zb + rb + ((((unsigned)i0 << 6) + ((unsigned)l15 << 1)) ^ swz))        = f2bf(acc00[q] * inv);
            *(unsigned short*)(zb + rb + ((((unsigned)i0 << 6) + ((unsigned)(16 + l15) << 1)) ^ swz)) = f2bf(acc01[q] * inv);
            *(unsigned short*)(zb + rb + ((((unsigned)i1 << 6) + ((unsigned)l15 << 1)) ^ swz))        = f2bf(acc10[q] * inv);
            *(unsigned short*)(zb + rb + ((((unsigned)i1 << 6) + ((unsigned)(16 + l15) << 1)) ^ swz)) = f2bf(acc11[q] * inv);
        }
        if (lane < 32) {                                 // slot b=30: xself for i in wave's range
            unsigned by = (((unsigned)(((mh << 5) + lane) << 6)) + 60u) ^ swz;
            *(unsigned short*)(zb + rb + by) = f2bf(xselfv);
            if (mh == 0 && lane == 0)                    // slot b=31 @ i=0: 1.0 (bias hot-one)
                *(unsigned short*)(zb + rb + (62u ^ swz)) = (unsigned short)0x3F80;
        }
    };

    do_round((w >> 1),     offA0, offA1, xsA);
    do_round((w >> 1) + 8, offB0, offB1, xsB);
    __syncthreads();

    // ---- phase 2 (verified): wave w -> colblk=w&3, K-quarter kq=w>>2 (512 each, 16 steps);
    //      B loads contiguous 1KB/step from fragment-ordered bbT
    {
        int colblk = w & 3, kq = w >> 2;
        const char* bp2 = (const char*)bbT + (((unsigned)(colblk * 4 + kq)) << 14) + ((unsigned)lane << 4);
        unsigned arow = (unsigned)l15 << 12;
        unsigned aswz = (unsigned)((l15 & 7) << 4);
        f32x4 acc2 = {0.f,0.f,0.f,0.f};
#pragma unroll 4
        for (int s = 0; s < 16; ++s) {
            unsigned abyte = ((unsigned)((kq << 10) + (s << 6) + (lk << 4))) ^ aswz;
            short8v a = *(const short8v*)(zb + arow + abyte);
            short8v b = *(const short8v*)(bp2 + (s << 10));
            acc2 = __builtin_amdgcn_mfma_f32_16x16x32_bf16(a, b, acc2, 0, 0, 0);
        }
#pragma unroll
        for (int q = 0; q < 4; ++q)                      // D: col=l15, row=lk*4+q (row = target)
            pf[(w << 8) + ((lk << 2) + q) * 16 + l15] = acc2[q];
    }
    __syncthreads();

    // ---- reduce 4 K-quarters + write (1024 threads = 16 targets x 64 cols)
    {
        int row = w, col = lane;
        int cb = col >> 4, cl = col & 15;
        int tt = t0 + row;
        if (tt < N) {
            float v = pf[(((0 << 2) + cb) << 8) + (row << 4) + cl]
                    + pf[(((1 << 2) + cb) << 8) + (row << 4) + cl]
                    + pf[(((2 << 2) + cb) << 8) + (row << 4) + cl]
                    + pf[(((3 << 2) + cb) << 8) + (row << 4) + cl];
            out[((size_t)tt << 6) + col] = v;
        }
    }
}

extern "C" void kernel_launch(void* const* d_in, const int* in_sizes, int n_in,
                              void* d_out, int out_size, void* d_ws, size_t ws_size,
                              hipStream_t stream) {
    const float* x     = (const float*)d_in[0];
    const int*   eidx  = (const int*)d_in[1];   // (2, E)
    const int*   etype = (const int*)d_in[2];
    const float* basis = (const float*)d_in[4];
    const float* coeff = (const float*)d_in[5];
    const float* sw    = (const float*)d_in[6];
    const float* bias  = (const float*)d_in[7];

    const int E = in_sizes[1] / 2;
    const int N = out_size / OUT_F;
    const int NB = (N + 255) >> 8;
    const int* srcv = eidx;
    const int* tgtv = eidx + E;
    float* out = (float*)d_out;

    size_t p = 0;
    auto alloc = [&](size_t bytes) { size_t cur = p; p += (bytes + 255) & ~(size_t)255; return cur; };
    char* base = (char*)d_ws;
    __hip_bfloat16* bbT   = (__hip_bfloat16*)(base + alloc((size_t)OUT_F * KROW * 2));
    int*            gsum  = (int*)(base + alloc(256 * 4));
    int*            gexcl = (int*)(base + alloc((size_t)(NB + 1) * 4));
    int*            bcur  = (int*)(base + alloc((size_t)NB * 4));
    int*            off   = (int*)(base + alloc((size_t)(N + 1) * 4));
    unsigned*       ssr   = (unsigned*)(base + alloc((size_t)E * 4));
    unsigned*       ssr2  = (unsigned*)(base + alloc((size_t)E * 4));
    unsigned*       xh    = (unsigned*)(base + alloc((size_t)N * 32 * 4));
    (void)ws_size;

    hipMemsetAsync(gsum, 0, 256 * 4, stream);

    k_bbt<<<(OUT_F * KROW + 255) / 256, 256, 0, stream>>>(basis, sw, bias, bbT);
    k_xpack<<<(N * 32 + 255) / 256, 256, 0, stream>>>(x, xh, N);
    k_b1a<<<256, 256, 0, stream>>>(tgtv, gsum, E);
    k_scanB<<<1, 64, 0, stream>>>(gsum, gexcl, bcur, off, NB, N);
    k_b1<<<(E + B1CHUNK - 1) / B1CHUNK, 1024, 0, stream>>>(srcv, tgtv, etype, bcur, ssr, E);
    k_b2<<<NB, 256, 0, stream>>>(ssr, gexcl, off, ssr2, N);
    k_fused<<<(N + 15) / 16, 1024, 0, stream>>>(x, xh, ssr2, off, coeff, bbT, out, N);
}